// Round 15
// baseline (309.831 us; speedup 1.0000x reference)
//
#include <hip/hip_runtime.h>
#include <hip/hip_bf16.h>
#include <math.h>

#define NHH 16
#define SS  2048
#define TT  4096            // B*S tokens
#define DQK 192
#define QSCALE 0.07216878364870322f   // 1/sqrt(192)
#define ROPE_C 0.28782313662425574f   // 2*ln(10000)/64

typedef __bf16 bf16x8 __attribute__((ext_vector_type(8)));
typedef float f32x4 __attribute__((ext_vector_type(4)));
typedef unsigned long long u64;

#define GLOAD16(gp, lp) __builtin_amdgcn_global_load_lds( \
    (const __attribute__((address_space(1))) void*)(gp),  \
    (__attribute__((address_space(3))) void*)(lp), 16, 0, 0)

// ---------------------------------------------------------------------------
// Fused fp32 -> bf16 cast of x + all 7 weight tensors, plus RoPE cos/sin
// table (2048 x 32 float2) in the trailing 32 blocks.
// ---------------------------------------------------------------------------
#define SEG0 8388608     // x
#define SEG1 11534336    // + wq_down (3145728)
#define SEG2 12582912    // + wkv_down (1048576)
#define SEG3 12713984    // + wk_rope (131072)
#define SEG4 15859712    // + wq_up (3145728)
#define SEG5 17432576    // + wq_rope (1572864)
#define SEG6 19529728    // + wkv_up (2097152)
#define SEG7 23724032    // + wo (4194304)
#define NBCAST (SEG7 / 2048)

__global__ __launch_bounds__(256) void cast_all(
        const float* __restrict__ x, const float* __restrict__ wqd,
        const float* __restrict__ wkvd, const float* __restrict__ wkr,
        const float* __restrict__ wqu, const float* __restrict__ wqr,
        const float* __restrict__ wkvu, const float* __restrict__ wo,
        __bf16* __restrict__ xb, __bf16* __restrict__ wqd_b,
        __bf16* __restrict__ wkvd_b, __bf16* __restrict__ wkr_b,
        __bf16* __restrict__ wqu_b, __bf16* __restrict__ wqr_b,
        __bf16* __restrict__ wkvu_b, __bf16* __restrict__ wo_b,
        float2* __restrict__ CS) {
    if (blockIdx.x >= NBCAST) {
        // RoPE table: entry e -> spos = e>>5, fi = e&31
        const int e0 = ((blockIdx.x - NBCAST) * 256 + threadIdx.x) * 8;
#pragma unroll
        for (int k = 0; k < 8; ++k) {
            const int e = e0 + k;
            const int spos = e >> 5, fi = e & 31;
            const float ang = (float)spos * expf(-ROPE_C * (float)fi);
            CS[e] = make_float2(cosf(ang), sinf(ang));
        }
        return;
    }
    const int i = (blockIdx.x * 256 + threadIdx.x) * 8;
    const float* src;
    __bf16* dst;
    int off;
    if (i < SEG0)      { src = x;    dst = xb;     off = i; }
    else if (i < SEG1) { src = wqd;  dst = wqd_b;  off = i - SEG0; }
    else if (i < SEG2) { src = wkvd; dst = wkvd_b; off = i - SEG1; }
    else if (i < SEG3) { src = wkr;  dst = wkr_b;  off = i - SEG2; }
    else if (i < SEG4) { src = wqu;  dst = wqu_b;  off = i - SEG3; }
    else if (i < SEG5) { src = wqr;  dst = wqr_b;  off = i - SEG4; }
    else if (i < SEG6) { src = wkvu; dst = wkvu_b; off = i - SEG5; }
    else               { src = wo;   dst = wo_b;   off = i - SEG6; }
    const float4 a = *(const float4*)(src + off);
    const float4 b = *(const float4*)(src + off + 4);
    __bf16 o[8] = {(__bf16)a.x, (__bf16)a.y, (__bf16)a.z, (__bf16)a.w,
                   (__bf16)b.x, (__bf16)b.y, (__bf16)b.z, (__bf16)b.w};
    *(bf16x8*)(dst + off) = *(const bf16x8*)o;
}

// ---------------------------------------------------------------------------
// Merged RMSNorm: rows 0..4095 -> q_c (N=1536), rows 4096..8191 -> kv_c (512)
// ---------------------------------------------------------------------------
__global__ __launch_bounds__(256) void rmsnorm2(
        const float* __restrict__ qc, const float* __restrict__ kvc,
        __bf16* __restrict__ qcb, __bf16* __restrict__ kvcb,
        const float* __restrict__ wq, const float* __restrict__ wkv) {
    const int row = blockIdx.x;
    const float* xr;
    __bf16* orow;
    const float* w;
    int N;
    if (row < TT) { xr = qc + (size_t)row * 1536;         orow = qcb + (size_t)row * 1536;         w = wq;  N = 1536; }
    else          { xr = kvc + (size_t)(row - TT) * 512;  orow = kvcb + (size_t)(row - TT) * 512;  w = wkv; N = 512; }
    float ss = 0.f;
    for (int i = threadIdx.x; i < N; i += 256) {
        float v = xr[i];
        ss += v * v;
    }
    __shared__ float red[256];
    red[threadIdx.x] = ss;
    __syncthreads();
    for (int s = 128; s > 0; s >>= 1) {
        if (threadIdx.x < s) red[threadIdx.x] += red[threadIdx.x + s];
        __syncthreads();
    }
    const float scale = rsqrtf(red[0] / (float)N + 1e-6f);
    for (int i = threadIdx.x; i < N; i += 256) orow[i] = (__bf16)(xr[i] * scale * w[i]);
}

// ---------------------------------------------------------------------------
// bf16 MFMA NT-GEMM v3 (R13/R14 passing core): BK=32, 3-buffer LDS at 72KB ->
// 2 blocks/CU; one barrier + one counted vmcnt per K-tile. RoPE epilogues now
// read the precomputed cos/sin table CS[spos*32+fi].
// ---------------------------------------------------------------------------
template<int MODE>
__global__ __launch_bounds__(512, 2) void gemm10(
        const __bf16* __restrict__ A,
        const __bf16* __restrict__ W0, const __bf16* __restrict__ W1,
        const __bf16* __restrict__ W2,
        float* __restrict__ F0, float* __restrict__ F1,
        __bf16* __restrict__ B0, __bf16* __restrict__ B1,
        const float2* __restrict__ CS,
        int M, int N, int Kin) {
    __shared__ __bf16 lds[3 * 12288];   // 3 x (A 128x32 + B 256x32) = 72KB
    const int tid = threadIdx.x;
    const int w = tid >> 6, l = tid & 63;
    const int lr = l & 15, lg = l >> 4;
    const int wm = w >> 2, wn = w & 3;

    int m0, n0, nlim = 256, K = Kin;
    bool isKV = false;
    const __bf16* Ause = A;
    if (MODE == 0) {
        const int fb = blockIdx.x;
        if (fb < 256) { m0 = (fb >> 3) * 128; n0 = (fb & 7) * 256; }
        else          { m0 = (fb - 256) * 128; n0 = 2048; }
        nlim = 2112 - n0;
    } else if (MODE == 1) {
        int fb = blockIdx.x;
        isKV = (fb >= 384);
        if (isKV) { fb -= 384; K = 512; Ause = (const __bf16*)F0; }
        m0 = (fb & 31) * 128;
        n0 = (fb >> 5) * 256;
    } else {
        m0 = blockIdx.y * 128; n0 = blockIdx.x * 256;
    }
    const bool fullB = (nlim >= 256);
    const bool wAct  = (wn * 64 < nlim);

    const int srow = tid >> 2;              // 0..127
    const int scol = (tid & 3) << 3;        // 0,8,16,24
    const int csw  = scol ^ (((srow >> 1) & 3) << 3);

    const __bf16* aptr = Ause + (size_t)(m0 + srow) * K + csw;

    const __bf16* bptr[2];
#pragma unroll
    for (int i = 0; i < 2; ++i) {
        const int row = i * 128 + srow;
        const int n = n0 + row;
        const __bf16* wp;
        if (MODE == 0) {
            if (n < 1536)      wp = W0 + (size_t)n * K;
            else if (n < 2048) wp = W1 + (size_t)(n - 1536) * K;
            else if (n < 2112) wp = W2 + (size_t)(n - 2048) * K;
            else               wp = W0;
        } else if (MODE == 1) {
            if (isKV)          wp = W2 + (size_t)n * K;
            else               wp = (n < 2048) ? W0 + (size_t)n * K
                                               : W1 + (size_t)(n - 2048) * K;
        } else {
            wp = W0 + (size_t)n * K;
        }
        bptr[i] = wp + csw;
    }

    auto stA = [&](int t2) {
        GLOAD16(aptr + (size_t)t2 * 32, &lds[(t2 % 3) * 12288 + tid * 8]);
    };
    auto stB = [&](int t2, int i) {
        GLOAD16(bptr[i] + (size_t)t2 * 32,
                &lds[(t2 % 3) * 12288 + 4096 + i * 4096 + tid * 8]);
    };

    const int rswz = ((lr >> 1) & 3) << 3;

    f32x4 acc[4][4];
#pragma unroll
    for (int i = 0; i < 4; ++i)
#pragma unroll
        for (int j = 0; j < 4; ++j) acc[i][j] = (f32x4){0.f, 0.f, 0.f, 0.f};

    const int NT = K >> 5;
    stA(0); stB(0, 0); if (fullB) stB(0, 1);
    stA(1); stB(1, 0); if (fullB) stB(1, 1);

    for (int t = 0; t < NT; ++t) {
        if (t + 1 < NT) {
            if (fullB) asm volatile("s_waitcnt vmcnt(3)" ::: "memory");
            else       asm volatile("s_waitcnt vmcnt(2)" ::: "memory");
        } else {
            asm volatile("s_waitcnt vmcnt(0)" ::: "memory");
        }
        __builtin_amdgcn_s_barrier();

        const __bf16* As_ = &lds[(t % 3) * 12288];
        const __bf16* Bs_ = As_ + 4096;

        if (t + 2 < NT) {
            stA(t + 2); stB(t + 2, 0); if (fullB) stB(t + 2, 1);
        }

        if (wAct) {
            bf16x8 fa[4], fb[4];
#pragma unroll
            for (int i = 0; i < 4; ++i)
                fa[i] = *(const bf16x8*)&As_[(wm * 64 + i * 16 + lr) * 32 +
                                             ((lg * 8) ^ rswz)];
#pragma unroll
            for (int j = 0; j < 4; ++j)
                fb[j] = *(const bf16x8*)&Bs_[(wn * 64 + j * 16 + lr) * 32 +
                                             ((lg * 8) ^ rswz)];
            __builtin_amdgcn_s_setprio(1);
#pragma unroll
            for (int i = 0; i < 4; ++i)
#pragma unroll
                for (int j = 0; j < 4; ++j)
                    acc[i][j] = __builtin_amdgcn_mfma_f32_16x16x32_bf16(fa[i], fb[j], acc[i][j], 0, 0, 0);
            __builtin_amdgcn_s_setprio(0);
        }
    }

    if (!wAct) return;

#pragma unroll
    for (int i = 0; i < 4; ++i) {
#pragma unroll
        for (int j = 0; j < 4; ++j) {
#pragma unroll
            for (int r = 0; r < 4; ++r) {
                const int m = m0 + wm * 64 + i * 16 + lg * 4 + r;
                const int n = n0 + wn * 64 + j * 16 + lr;
                const float v = acc[i][j][r];
                float vp = 0.f;
                if (MODE == 0 || MODE == 1) vp = __shfl_xor(v, 1);  // rope partner
                if (MODE == 0) {
                    if (n < 1536) {
                        F0[(size_t)m * 1536 + n] = v;
                    } else if (n < 2048) {
                        F1[(size_t)m * 512 + (n - 1536)] = v;
                    } else if (n < 2112) {
                        const int jj = n - 2048;
                        const int fi = jj >> 1;
                        const int spos = m & (SS - 1);
                        const float2 cs = CS[spos * 32 + fi];
                        const float o = (jj & 1) ? (vp * cs.y + v * cs.x) : (v * cs.x - vp * cs.y);
                        B0[(size_t)m * 64 + jj] = (__bf16)o;
                    }
                } else if (MODE == 1) {
                    if (!isKV) {
                        if (n < 2048) {
                            B0[(size_t)m * 3072 + (n >> 7) * 192 + (n & 127)] = (__bf16)(v * QSCALE);
                        } else {
                            const int jj = n - 2048;
                            const int h = jj >> 6, dd = jj & 63;
                            const int fi = dd >> 1;
                            const int spos = m & (SS - 1);
                            const float2 cs = CS[spos * 32 + fi];
                            const float o = (dd & 1) ? (vp * cs.y + v * cs.x) : (v * cs.x - vp * cs.y);
                            B0[(size_t)m * 3072 + h * 192 + 128 + dd] = (__bf16)(o * QSCALE);
                        }
                    } else {
                        __bf16* vTo = (__bf16*)F1;
                        const int h = n >> 8, off = n & 255;
                        if (off < 128)
                            B1[(size_t)m * 2048 + h * 128 + off] = (__bf16)v;
                        else
                            vTo[(((size_t)(m >> 11) * NHH + h) * 128 + (off - 128)) * SS + (m & (SS - 1))] = (__bf16)v;
                    }
                } else {
                    F0[(size_t)m * N + n] = v;
                }
            }
        }
    }
}

// ---------------------------------------------------------------------------
// MFMA flash attention v9 (R14 passing version, unchanged): swapped-operand
// QK^T, per-lane softmax, vector P store, cross-tile wave grouping.
// ---------------------------------------------------------------------------
__global__ __launch_bounds__(512, 1) void attn_mfma9(
        const __bf16* __restrict__ q, const __bf16* __restrict__ knope,
        const __bf16* __restrict__ krope, const __bf16* __restrict__ vT,
        __bf16* __restrict__ att) {
    const int flat = blockIdx.x;
    const int xcd = flat & 7;
    const int a0 = flat >> 3;
    const int bx = a0 & 7;
    const int g8 = ((a0 >> 3) << 3) | xcd;
    const int h = g8 & 15;
    const int b = g8 >> 4;

    const int tid = threadIdx.x;
    const int w  = tid >> 6;
    const int l  = tid & 63;
    const int lr = l & 15;
    const int lg = l >> 4;

    __shared__ __bf16 Ks[2][64][200];
    __shared__ __bf16 Vs[2][128][72];
    __shared__ __bf16 Ps[8][2][16][72];

    const int rg[2] = {bx * 128 + w * 16, (15 - bx) * 128 + w * 16};
    const int nkt = 2 * (15 - bx) + 2;

    bf16x8 sreg[5];
    auto stage_load = [&](int kv0) {
#pragma unroll
        for (int i = 0; i < 5; ++i) {
            const int gc = tid + 512 * i;
            if (gc < 1536) {
                const int row = gc / 24, cc = gc - row * 24;
                const size_t tt = (size_t)(b * SS + kv0 + row);
                const __bf16* src = (cc < 16)
                    ? knope + tt * 2048 + h * 128 + cc * 8
                    : krope + tt * 64 + (cc - 16) * 8;
                sreg[i] = *(const bf16x8*)src;
            } else {
                const int c = gc - 1536;
                const int row = c >> 3, cc = c & 7;
                sreg[i] = *(const bf16x8*)(vT + (((size_t)b * NHH + h) * 128 + row) * SS
                                              + kv0 + cc * 8);
            }
        }
    };
    auto stage_write = [&](int bi) {
#pragma unroll
        for (int i = 0; i < 5; ++i) {
            const int gc = tid + 512 * i;
            if (gc < 1536) {
                const int row = gc / 24, cc = gc - row * 24;
                *(bf16x8*)&Ks[bi][row][cc * 8] = sreg[i];
            } else {
                const int c = gc - 1536;
                *(bf16x8*)&Vs[bi][c >> 3][(c & 7) * 8] = sreg[i];
            }
        }
    };

    bf16x8 qf[2][6];
#pragma unroll
    for (int grp = 0; grp < 2; ++grp) {
        const __bf16* qb = q + (((size_t)(b * SS + rg[grp] + lr)) * NHH + h) * DQK + lg * 8;
#pragma unroll
        for (int c = 0; c < 6; ++c) qf[grp][c] = *(const bf16x8*)(qb + c * 32);
    }

    f32x4 O[2][8];
    float m_s[2], l_s[2];
#pragma unroll
    for (int grp = 0; grp < 2; ++grp) {
#pragma unroll
        for (int n = 0; n < 8; ++n) O[grp][n] = (f32x4){0.f, 0.f, 0.f, 0.f};
        m_s[grp] = -INFINITY; l_s[grp] = 0.f;
    }

    stage_load(0);
    stage_write(0);
    __syncthreads();
    int cur = 0;

    for (int kt = 0; kt < nkt; ++kt) {
        const int kv0 = kt * 64;
        const bool hasNext = (kt + 1 < nkt);
        if (hasNext) stage_load(kv0 + 64);

        const bool act0 = kv0 <= rg[0] + 15;
        const bool act1 = kv0 <= rg[1] + 15;
        if (act1 || act0) {
            // ---- QK^T (swapped): D[kv][q], lane lr = q-row ----
            f32x4 sc[2][4];
#pragma unroll
            for (int s = 0; s < 4; ++s) {
                const int colb = kv0 + s * 16;
                if (colb <= rg[1] + 15 || colb <= rg[0] + 15) {
                    bf16x8 kf[6];
#pragma unroll
                    for (int c = 0; c < 6; ++c)
                        kf[c] = *(const bf16x8*)&Ks[cur][s * 16 + lr][c * 32 + lg * 8];
                    __builtin_amdgcn_s_setprio(1);
#pragma unroll
                    for (int grp = 0; grp < 2; ++grp) {
                        if (colb <= rg[grp] + 15) {
                            f32x4 acc = (f32x4){0.f, 0.f, 0.f, 0.f};
#pragma unroll
                            for (int c = 0; c < 6; ++c)
                                acc = __builtin_amdgcn_mfma_f32_16x16x32_bf16(kf[c], qf[grp][c], acc, 0, 0, 0);
                            sc[grp][s] = acc;
                        } else {
                            sc[grp][s] = (f32x4){-INFINITY, -INFINITY, -INFINITY, -INFINITY};
                        }
                    }
                    __builtin_amdgcn_s_setprio(0);
                } else {
                    sc[0][s] = (f32x4){-INFINITY, -INFINITY, -INFINITY, -INFINITY};
                    sc[1][s] = (f32x4){-INFINITY, -INFINITY, -INFINITY, -INFINITY};
                }
            }

            // ---- per-lane softmax (defer-max) + vector P store ----
#pragma unroll
            for (int grp = 0; grp < 2; ++grp) {
                const bool act = (grp == 0) ? act0 : act1;
                if (!act) continue;
                const int qrow = rg[grp] + lr;
#pragma unroll
                for (int s = 0; s < 4; ++s) {
#pragma unroll
                    for (int r = 0; r < 4; ++r)
                        if (kv0 + s * 16 + lg * 4 + r > qrow) sc[grp][s][r] = -INFINITY;
                }
                float mt = sc[grp][0][0];
#pragma unroll
                for (int s = 0; s < 4; ++s)
#pragma unroll
                    for (int r = 0; r < 4; ++r) mt = fmaxf(mt, sc[grp][s][r]);
                mt = fmaxf(mt, __shfl_xor(mt, 16));
                mt = fmaxf(mt, __shfl_xor(mt, 32));
                const bool ok = (mt <= m_s[grp] + 8.f);
                if (!__all(ok)) {
                    const float mn = fmaxf(m_s[grp], mt);
                    const float al = __expf(m_s[grp] - mn);
                    m_s[grp] = mn;
                    l_s[grp] *= al;
                    float al4[4];
#pragma unroll
                    for (int r = 0; r < 4; ++r) al4[r] = __shfl(al, lg * 4 + r);
#pragma unroll
                    for (int n = 0; n < 8; ++n)
#pragma unroll
                        for (int r = 0; r < 4; ++r) O[grp][n][r] *= al4[r];
                }
                float ls = 0.f;
#pragma unroll
                for (int s = 0; s < 4; ++s) {
                    float pv[4];
#pragma unroll
                    for (int r = 0; r < 4; ++r) pv[r] = __expf(sc[grp][s][r] - m_s[grp]);
                    ls += (pv[0] + pv[1]) + (pv[2] + pv[3]);
                    union { __bf16 hh[4]; u64 u; } pk;
                    pk.hh[0] = (__bf16)pv[0]; pk.hh[1] = (__bf16)pv[1];
                    pk.hh[2] = (__bf16)pv[2]; pk.hh[3] = (__bf16)pv[3];
                    *(u64*)&Ps[w][grp][lr][s * 16 + lg * 4] = pk.u;
                }
                ls += __shfl_xor(ls, 16);
                ls += __shfl_xor(ls, 32);
                l_s[grp] += ls;
            }

            // ---- P read + PV ----
            bf16x8 pf[2][2];
#pragma unroll
            for (int grp = 0; grp < 2; ++grp)
#pragma unroll
                for (int ks = 0; ks < 2; ++ks)
                    pf[grp][ks] = *(const bf16x8*)&Ps[w][grp][lr][ks * 32 + lg * 8];
#pragma unroll
            for (int n = 0; n < 8; ++n) {
                bf16x8 v0 = *(const bf16x8*)&Vs[cur][n * 16 + lr][lg * 8];
                bf16x8 v1 = *(const bf16x8*)&Vs[cur][n * 16 + lr][32 + lg * 8];
                __builtin_amdgcn_s_setprio(1);
                if (act0) {
                    O[0][n] = __builtin_amdgcn_mfma_f32_16x16x32_bf16(pf[0][0], v0, O[0][n], 0, 0, 0);
                    O[0][n] = __builtin_amdgcn_mfma_f32_16x16x32_bf16(pf[0][1], v1, O[0][n], 0, 0, 0);
                }
                if (act1) {
                    O[1][n] = __builtin_amdgcn_mfma_f32_16x16x32_bf16(pf[1][0], v0, O[1][n], 0, 0, 0);
                    O[1][n] = __builtin_amdgcn_mfma_f32_16x16x32_bf16(pf[1][1], v1, O[1][n], 0, 0, 0);
                }
                __builtin_amdgcn_s_setprio(0);
            }
        }

        if (hasNext) stage_write(cur ^ 1);
        __syncthreads();
        cur ^= 1;
    }

    // ---- epilogue ----
#pragma unroll
    for (int grp = 0; grp < 2; ++grp) {
        const float invl = 1.0f / l_s[grp];
        float inv[4];
#pragma unroll
        for (int r = 0; r < 4; ++r) inv[r] = __shfl(invl, lg * 4 + r);
#pragma unroll
        for (int n = 0; n < 8; ++n) {
#pragma unroll
            for (int r = 0; r < 4; ++r) {
                const size_t tt = (size_t)(b * SS + rg[grp] + lg * 4 + r);
                att[(tt * NHH + h) * 128 + n * 16 + lr] = (__bf16)(O[grp][n][r] * inv[r]);
            }
        }
    }
}

// ---------------------------------------------------------------------------
extern "C" void kernel_launch(void* const* d_in, const int* in_sizes, int n_in,
                              void* d_out, int out_size, void* d_ws, size_t ws_size,
                              hipStream_t stream) {
    (void)in_sizes; (void)n_in; (void)out_size; (void)ws_size;
    const float* x        = (const float*)d_in[0];
    const float* wq_down  = (const float*)d_in[1];
    const float* wq_up    = (const float*)d_in[2];
    const float* wq_rope  = (const float*)d_in[3];
    const float* q_norm_w = (const float*)d_in[4];
    const float* wkv_down = (const float*)d_in[5];
    const float* kv_norm_w= (const float*)d_in[6];
    const float* wkv_up   = (const float*)d_in[7];
    const float* wk_rope  = (const float*)d_in[8];
    const float* wo       = (const float*)d_in[9];
    float* out = (float*)d_out;

    char* ws = (char*)d_ws;
    float*  q_c   = (float*)(ws + 0);            // 24MB fp32 [4096][1536]
    __bf16* att   = (__bf16*)(ws + 0);           // 16MB bf16, aliases dead q_c
    float*  kv_c  = (float*)(ws + 25165824);     // 8MB fp32 [4096][512]
    __bf16* xb    = (__bf16*)(ws + 33554432);    // 16MB bf16 [4096][2048]
    __bf16* vT    = (__bf16*)(ws + 33554432);    // 16MB bf16, aliases dead xb
    __bf16* qc_b  = (__bf16*)(ws + 50331648);    // 12MB bf16 [4096][1536]
    __bf16* kvc_b = (__bf16*)(ws + 62914560);    // 4MB bf16 [4096][512]
    __bf16* krope = (__bf16*)(ws + 67108864);    // 0.5MB bf16 [4096][64]
    __bf16* qbuf  = (__bf16*)(ws + 67633152);    // 24MB bf16 [4096][3072]
    __bf16* wqd_b = (__bf16*)(ws + 92798976);    // 6MB
    __bf16* wqu_b = (__bf16*)(ws + 99090432);    // 6MB
    __bf16* wqr_b = (__bf16*)(ws + 105381888);   // 3MB
    __bf16* wkvd_b= (__bf16*)(ws + 108527616);   // 2MB
    __bf16* wkvu_b= (__bf16*)(ws + 110624768);   // 4MB
    __bf16* wkr_b = (__bf16*)(ws + 114819072);   // 0.25MB
    __bf16* wo_b  = (__bf16*)(ws + 115081216);   // 8MB (end 123469824)
    __bf16* knope = (__bf16*)d_out;              // 16MB bf16 in first half of d_out
    float2* csTab = (float2*)((char*)d_out + 16777216); // 512KB in second half of d_out
                                                 // (dead before O-GEMM overwrites d_out)

    const dim3 blk(256);

    cast_all<<<dim3(NBCAST + 32), blk, 0, stream>>>(
        x, wq_down, wkv_down, wk_rope, wq_up, wq_rope, wkv_up, wo,
        xb, wqd_b, wkvd_b, wkr_b, wqu_b, wqr_b, wkvu_b, wo_b, csTab);

    // X-GEMM: 256 full tiles + 32 cheap strip tiles
    gemm10<0><<<dim3(288), dim3(512), 0, stream>>>(xb, wqd_b, wkvd_b, wkr_b,
                                                   q_c, kv_c, krope, nullptr, csTab,
                                                   TT, 2112, 2048);

    rmsnorm2<<<dim3(2 * TT), blk, 0, stream>>>(q_c, kv_c, qc_b, kvc_b, q_norm_w, kv_norm_w);

    // fused Q-GEMM (384 tiles) + KV-GEMM (512 tiles) in one 896-block launch
    gemm10<1><<<dim3(896), dim3(512), 0, stream>>>(qc_b, wqu_b, wqr_b, wkvu_b,
                                                   (float*)kvc_b, (float*)vT,
                                                   qbuf, knope, csTab, TT, 3072, 1536);

    attn_mfma9<<<dim3(256), dim3(512), 0, stream>>>(qbuf, knope, krope, vT, att);

    gemm10<3><<<dim3(8, 32), dim3(512), 0, stream>>>(att, wo_b, nullptr, nullptr,
                                                     out, nullptr, nullptr, nullptr, csTab,
                                                     TT, 2048, 2048);
}

// Round 16
// 298.111 us; speedup vs baseline: 1.0393x; 1.0393x over previous
//
#include <hip/hip_runtime.h>
#include <hip/hip_bf16.h>
#include <math.h>

#define NHH 16
#define SS  2048
#define TT  4096            // B*S tokens
#define DQK 192
#define QSCALE 0.07216878364870322f   // 1/sqrt(192)
#define ROPE_C 0.28782313662425574f   // 2*ln(10000)/64

typedef __bf16 bf16x8 __attribute__((ext_vector_type(8)));
typedef float f32x4 __attribute__((ext_vector_type(4)));
typedef unsigned long long u64;

#define GLOAD16(gp, lp) __builtin_amdgcn_global_load_lds( \
    (const __attribute__((address_space(1))) void*)(gp),  \
    (__attribute__((address_space(3))) void*)(lp), 16, 0, 0)

// ---------------------------------------------------------------------------
// Fused fp32 -> bf16 cast of x + all 7 weight tensors.
// ---------------------------------------------------------------------------
#define SEG0 8388608     // x
#define SEG1 11534336    // + wq_down (3145728)
#define SEG2 12582912    // + wkv_down (1048576)
#define SEG3 12713984    // + wk_rope (131072)
#define SEG4 15859712    // + wq_up (3145728)
#define SEG5 17432576    // + wq_rope (1572864)
#define SEG6 19529728    // + wkv_up (2097152)
#define SEG7 23724032    // + wo (4194304)

__global__ __launch_bounds__(256) void cast_all(
        const float* __restrict__ x, const float* __restrict__ wqd,
        const float* __restrict__ wkvd, const float* __restrict__ wkr,
        const float* __restrict__ wqu, const float* __restrict__ wqr,
        const float* __restrict__ wkvu, const float* __restrict__ wo,
        __bf16* __restrict__ xb, __bf16* __restrict__ wqd_b,
        __bf16* __restrict__ wkvd_b, __bf16* __restrict__ wkr_b,
        __bf16* __restrict__ wqu_b, __bf16* __restrict__ wqr_b,
        __bf16* __restrict__ wkvu_b, __bf16* __restrict__ wo_b) {
    const int i = (blockIdx.x * 256 + threadIdx.x) * 8;
    const float* src;
    __bf16* dst;
    int off;
    if (i < SEG0)      { src = x;    dst = xb;     off = i; }
    else if (i < SEG1) { src = wqd;  dst = wqd_b;  off = i - SEG0; }
    else if (i < SEG2) { src = wkvd; dst = wkvd_b; off = i - SEG1; }
    else if (i < SEG3) { src = wkr;  dst = wkr_b;  off = i - SEG2; }
    else if (i < SEG4) { src = wqu;  dst = wqu_b;  off = i - SEG3; }
    else if (i < SEG5) { src = wqr;  dst = wqr_b;  off = i - SEG4; }
    else if (i < SEG6) { src = wkvu; dst = wkvu_b; off = i - SEG5; }
    else               { src = wo;   dst = wo_b;   off = i - SEG6; }
    const float4 a = *(const float4*)(src + off);
    const float4 b = *(const float4*)(src + off + 4);
    __bf16 o[8] = {(__bf16)a.x, (__bf16)a.y, (__bf16)a.z, (__bf16)a.w,
                   (__bf16)b.x, (__bf16)b.y, (__bf16)b.z, (__bf16)b.w};
    *(bf16x8*)(dst + off) = *(const bf16x8*)o;
}

// ---------------------------------------------------------------------------
// Merged RMSNorm: rows 0..4095 -> q_c (N=1536), rows 4096..8191 -> kv_c (512)
// ---------------------------------------------------------------------------
__global__ __launch_bounds__(256) void rmsnorm2(
        const float* __restrict__ qc, const float* __restrict__ kvc,
        __bf16* __restrict__ qcb, __bf16* __restrict__ kvcb,
        const float* __restrict__ wq, const float* __restrict__ wkv) {
    const int row = blockIdx.x;
    const float* xr;
    __bf16* orow;
    const float* w;
    int N;
    if (row < TT) { xr = qc + (size_t)row * 1536;         orow = qcb + (size_t)row * 1536;         w = wq;  N = 1536; }
    else          { xr = kvc + (size_t)(row - TT) * 512;  orow = kvcb + (size_t)(row - TT) * 512;  w = wkv; N = 512; }
    float ss = 0.f;
    for (int i = threadIdx.x; i < N; i += 256) {
        float v = xr[i];
        ss += v * v;
    }
    __shared__ float red[256];
    red[threadIdx.x] = ss;
    __syncthreads();
    for (int s = 128; s > 0; s >>= 1) {
        if (threadIdx.x < s) red[threadIdx.x] += red[threadIdx.x + s];
        __syncthreads();
    }
    const float scale = rsqrtf(red[0] / (float)N + 1e-6f);
    for (int i = threadIdx.x; i < N; i += 256) orow[i] = (__bf16)(xr[i] * scale * w[i]);
}

// ---------------------------------------------------------------------------
// bf16 MFMA NT-GEMM v3 (R14 passing core, verbatim): BK=32, 3-buffer LDS at
// 72KB -> 2 blocks/CU; one barrier + one counted vmcnt per K-tile.
// ---------------------------------------------------------------------------
template<int MODE>
__global__ __launch_bounds__(512, 2) void gemm10(
        const __bf16* __restrict__ A,
        const __bf16* __restrict__ W0, const __bf16* __restrict__ W1,
        const __bf16* __restrict__ W2,
        float* __restrict__ F0, float* __restrict__ F1,
        __bf16* __restrict__ B0, __bf16* __restrict__ B1,
        int M, int N, int Kin) {
    __shared__ __bf16 lds[3 * 12288];   // 3 x (A 128x32 + B 256x32) = 72KB
    const int tid = threadIdx.x;
    const int w = tid >> 6, l = tid & 63;
    const int lr = l & 15, lg = l >> 4;
    const int wm = w >> 2, wn = w & 3;

    int m0, n0, nlim = 256, K = Kin;
    bool isKV = false;
    const __bf16* Ause = A;
    if (MODE == 0) {
        const int fb = blockIdx.x;
        if (fb < 256) { m0 = (fb >> 3) * 128; n0 = (fb & 7) * 256; }
        else          { m0 = (fb - 256) * 128; n0 = 2048; }
        nlim = 2112 - n0;
    } else if (MODE == 1) {
        int fb = blockIdx.x;
        isKV = (fb >= 384);
        if (isKV) { fb -= 384; K = 512; Ause = (const __bf16*)F0; }
        m0 = (fb & 31) * 128;
        n0 = (fb >> 5) * 256;
    } else {
        m0 = blockIdx.y * 128; n0 = blockIdx.x * 256;
    }
    const bool fullB = (nlim >= 256);
    const bool wAct  = (wn * 64 < nlim);

    const int srow = tid >> 2;              // 0..127
    const int scol = (tid & 3) << 3;        // 0,8,16,24
    const int csw  = scol ^ (((srow >> 1) & 3) << 3);

    const __bf16* aptr = Ause + (size_t)(m0 + srow) * K + csw;

    const __bf16* bptr[2];
#pragma unroll
    for (int i = 0; i < 2; ++i) {
        const int row = i * 128 + srow;
        const int n = n0 + row;
        const __bf16* wp;
        if (MODE == 0) {
            if (n < 1536)      wp = W0 + (size_t)n * K;
            else if (n < 2048) wp = W1 + (size_t)(n - 1536) * K;
            else if (n < 2112) wp = W2 + (size_t)(n - 2048) * K;
            else               wp = W0;
        } else if (MODE == 1) {
            if (isKV)          wp = W2 + (size_t)n * K;
            else               wp = (n < 2048) ? W0 + (size_t)n * K
                                               : W1 + (size_t)(n - 2048) * K;
        } else {
            wp = W0 + (size_t)n * K;
        }
        bptr[i] = wp + csw;
    }

    auto stA = [&](int t2) {
        GLOAD16(aptr + (size_t)t2 * 32, &lds[(t2 % 3) * 12288 + tid * 8]);
    };
    auto stB = [&](int t2, int i) {
        GLOAD16(bptr[i] + (size_t)t2 * 32,
                &lds[(t2 % 3) * 12288 + 4096 + i * 4096 + tid * 8]);
    };

    const int rswz = ((lr >> 1) & 3) << 3;

    f32x4 acc[4][4];
#pragma unroll
    for (int i = 0; i < 4; ++i)
#pragma unroll
        for (int j = 0; j < 4; ++j) acc[i][j] = (f32x4){0.f, 0.f, 0.f, 0.f};

    const int NT = K >> 5;
    stA(0); stB(0, 0); if (fullB) stB(0, 1);
    stA(1); stB(1, 0); if (fullB) stB(1, 1);

    for (int t = 0; t < NT; ++t) {
        if (t + 1 < NT) {
            if (fullB) asm volatile("s_waitcnt vmcnt(3)" ::: "memory");
            else       asm volatile("s_waitcnt vmcnt(2)" ::: "memory");
        } else {
            asm volatile("s_waitcnt vmcnt(0)" ::: "memory");
        }
        __builtin_amdgcn_s_barrier();

        const __bf16* As_ = &lds[(t % 3) * 12288];
        const __bf16* Bs_ = As_ + 4096;

        if (t + 2 < NT) {
            stA(t + 2); stB(t + 2, 0); if (fullB) stB(t + 2, 1);
        }

        if (wAct) {
            bf16x8 fa[4], fb[4];
#pragma unroll
            for (int i = 0; i < 4; ++i)
                fa[i] = *(const bf16x8*)&As_[(wm * 64 + i * 16 + lr) * 32 +
                                             ((lg * 8) ^ rswz)];
#pragma unroll
            for (int j = 0; j < 4; ++j)
                fb[j] = *(const bf16x8*)&Bs_[(wn * 64 + j * 16 + lr) * 32 +
                                             ((lg * 8) ^ rswz)];
            __builtin_amdgcn_s_setprio(1);
#pragma unroll
            for (int i = 0; i < 4; ++i)
#pragma unroll
                for (int j = 0; j < 4; ++j)
                    acc[i][j] = __builtin_amdgcn_mfma_f32_16x16x32_bf16(fa[i], fb[j], acc[i][j], 0, 0, 0);
            __builtin_amdgcn_s_setprio(0);
        }
    }

    if (!wAct) return;

#pragma unroll
    for (int i = 0; i < 4; ++i) {
#pragma unroll
        for (int j = 0; j < 4; ++j) {
#pragma unroll
            for (int r = 0; r < 4; ++r) {
                const int m = m0 + wm * 64 + i * 16 + lg * 4 + r;
                const int n = n0 + wn * 64 + j * 16 + lr;
                const float v = acc[i][j][r];
                float vp = 0.f;
                if (MODE == 0 || MODE == 1) vp = __shfl_xor(v, 1);  // rope partner
                if (MODE == 0) {
                    if (n < 1536) {
                        F0[(size_t)m * 1536 + n] = v;
                    } else if (n < 2048) {
                        F1[(size_t)m * 512 + (n - 1536)] = v;
                    } else if (n < 2112) {
                        const int jj = n - 2048;
                        const int fi = jj >> 1;
                        const int spos = m & (SS - 1);
                        const float freq = __expf(-ROPE_C * (float)fi);
                        const float ang = (float)spos * freq;
                        const float sn = __sinf(ang), cs = __cosf(ang);
                        const float o = (jj & 1) ? (vp * sn + v * cs) : (v * cs - vp * sn);
                        B0[(size_t)m * 64 + jj] = (__bf16)o;
                    }
                } else if (MODE == 1) {
                    if (!isKV) {
                        if (n < 2048) {
                            B0[(size_t)m * 3072 + (n >> 7) * 192 + (n & 127)] = (__bf16)(v * QSCALE);
                        } else {
                            const int jj = n - 2048;
                            const int h = jj >> 6, dd = jj & 63;
                            const int fi = dd >> 1;
                            const int spos = m & (SS - 1);
                            const float freq = __expf(-ROPE_C * (float)fi);
                            const float ang = (float)spos * freq;
                            const float sn = __sinf(ang), cs = __cosf(ang);
                            const float o = (dd & 1) ? (vp * sn + v * cs) : (v * cs - vp * sn);
                            B0[(size_t)m * 3072 + h * 192 + 128 + dd] = (__bf16)(o * QSCALE);
                        }
                    } else {
                        __bf16* vTo = (__bf16*)F1;
                        const int h = n >> 8, off = n & 255;
                        if (off < 128)
                            B1[(size_t)m * 2048 + h * 128 + off] = (__bf16)v;
                        else
                            vTo[(((size_t)(m >> 11) * NHH + h) * 128 + (off - 128)) * SS + (m & (SS - 1))] = (__bf16)v;
                    }
                } else {
                    F0[(size_t)m * N + n] = v;
                }
            }
        }
    }
}

// ---------------------------------------------------------------------------
// MFMA flash attention v9 (R14 passing version, verbatim): swapped-operand
// QK^T, per-lane softmax, vector P store, cross-tile wave grouping.
// ---------------------------------------------------------------------------
__global__ __launch_bounds__(512, 1) void attn_mfma9(
        const __bf16* __restrict__ q, const __bf16* __restrict__ knope,
        const __bf16* __restrict__ krope, const __bf16* __restrict__ vT,
        __bf16* __restrict__ att) {
    const int flat = blockIdx.x;
    const int xcd = flat & 7;
    const int a0 = flat >> 3;
    const int bx = a0 & 7;
    const int g8 = ((a0 >> 3) << 3) | xcd;
    const int h = g8 & 15;
    const int b = g8 >> 4;

    const int tid = threadIdx.x;
    const int w  = tid >> 6;
    const int l  = tid & 63;
    const int lr = l & 15;
    const int lg = l >> 4;

    __shared__ __bf16 Ks[2][64][200];
    __shared__ __bf16 Vs[2][128][72];
    __shared__ __bf16 Ps[8][2][16][72];

    const int rg[2] = {bx * 128 + w * 16, (15 - bx) * 128 + w * 16};
    const int nkt = 2 * (15 - bx) + 2;

    bf16x8 sreg[5];
    auto stage_load = [&](int kv0) {
#pragma unroll
        for (int i = 0; i < 5; ++i) {
            const int gc = tid + 512 * i;
            if (gc < 1536) {
                const int row = gc / 24, cc = gc - row * 24;
                const size_t tt = (size_t)(b * SS + kv0 + row);
                const __bf16* src = (cc < 16)
                    ? knope + tt * 2048 + h * 128 + cc * 8
                    : krope + tt * 64 + (cc - 16) * 8;
                sreg[i] = *(const bf16x8*)src;
            } else {
                const int c = gc - 1536;
                const int row = c >> 3, cc = c & 7;
                sreg[i] = *(const bf16x8*)(vT + (((size_t)b * NHH + h) * 128 + row) * SS
                                              + kv0 + cc * 8);
            }
        }
    };
    auto stage_write = [&](int bi) {
#pragma unroll
        for (int i = 0; i < 5; ++i) {
            const int gc = tid + 512 * i;
            if (gc < 1536) {
                const int row = gc / 24, cc = gc - row * 24;
                *(bf16x8*)&Ks[bi][row][cc * 8] = sreg[i];
            } else {
                const int c = gc - 1536;
                *(bf16x8*)&Vs[bi][c >> 3][(c & 7) * 8] = sreg[i];
            }
        }
    };

    bf16x8 qf[2][6];
#pragma unroll
    for (int grp = 0; grp < 2; ++grp) {
        const __bf16* qb = q + (((size_t)(b * SS + rg[grp] + lr)) * NHH + h) * DQK + lg * 8;
#pragma unroll
        for (int c = 0; c < 6; ++c) qf[grp][c] = *(const bf16x8*)(qb + c * 32);
    }

    f32x4 O[2][8];
    float m_s[2], l_s[2];
#pragma unroll
    for (int grp = 0; grp < 2; ++grp) {
#pragma unroll
        for (int n = 0; n < 8; ++n) O[grp][n] = (f32x4){0.f, 0.f, 0.f, 0.f};
        m_s[grp] = -INFINITY; l_s[grp] = 0.f;
    }

    stage_load(0);
    stage_write(0);
    __syncthreads();
    int cur = 0;

    for (int kt = 0; kt < nkt; ++kt) {
        const int kv0 = kt * 64;
        const bool hasNext = (kt + 1 < nkt);
        if (hasNext) stage_load(kv0 + 64);

        const bool act0 = kv0 <= rg[0] + 15;
        const bool act1 = kv0 <= rg[1] + 15;
        if (act1 || act0) {
            // ---- QK^T (swapped): D[kv][q], lane lr = q-row ----
            f32x4 sc[2][4];
#pragma unroll
            for (int s = 0; s < 4; ++s) {
                const int colb = kv0 + s * 16;
                if (colb <= rg[1] + 15 || colb <= rg[0] + 15) {
                    bf16x8 kf[6];
#pragma unroll
                    for (int c = 0; c < 6; ++c)
                        kf[c] = *(const bf16x8*)&Ks[cur][s * 16 + lr][c * 32 + lg * 8];
                    __builtin_amdgcn_s_setprio(1);
#pragma unroll
                    for (int grp = 0; grp < 2; ++grp) {
                        if (colb <= rg[grp] + 15) {
                            f32x4 acc = (f32x4){0.f, 0.f, 0.f, 0.f};
#pragma unroll
                            for (int c = 0; c < 6; ++c)
                                acc = __builtin_amdgcn_mfma_f32_16x16x32_bf16(kf[c], qf[grp][c], acc, 0, 0, 0);
                            sc[grp][s] = acc;
                        } else {
                            sc[grp][s] = (f32x4){-INFINITY, -INFINITY, -INFINITY, -INFINITY};
                        }
                    }
                    __builtin_amdgcn_s_setprio(0);
                } else {
                    sc[0][s] = (f32x4){-INFINITY, -INFINITY, -INFINITY, -INFINITY};
                    sc[1][s] = (f32x4){-INFINITY, -INFINITY, -INFINITY, -INFINITY};
                }
            }

            // ---- per-lane softmax (defer-max) + vector P store ----
#pragma unroll
            for (int grp = 0; grp < 2; ++grp) {
                const bool act = (grp == 0) ? act0 : act1;
                if (!act) continue;
                const int qrow = rg[grp] + lr;
#pragma unroll
                for (int s = 0; s < 4; ++s) {
#pragma unroll
                    for (int r = 0; r < 4; ++r)
                        if (kv0 + s * 16 + lg * 4 + r > qrow) sc[grp][s][r] = -INFINITY;
                }
                float mt = sc[grp][0][0];
#pragma unroll
                for (int s = 0; s < 4; ++s)
#pragma unroll
                    for (int r = 0; r < 4; ++r) mt = fmaxf(mt, sc[grp][s][r]);
                mt = fmaxf(mt, __shfl_xor(mt, 16));
                mt = fmaxf(mt, __shfl_xor(mt, 32));
                const bool ok = (mt <= m_s[grp] + 8.f);
                if (!__all(ok)) {
                    const float mn = fmaxf(m_s[grp], mt);
                    const float al = __expf(m_s[grp] - mn);
                    m_s[grp] = mn;
                    l_s[grp] *= al;
                    float al4[4];
#pragma unroll
                    for (int r = 0; r < 4; ++r) al4[r] = __shfl(al, lg * 4 + r);
#pragma unroll
                    for (int n = 0; n < 8; ++n)
#pragma unroll
                        for (int r = 0; r < 4; ++r) O[grp][n][r] *= al4[r];
                }
                float ls = 0.f;
#pragma unroll
                for (int s = 0; s < 4; ++s) {
                    float pv[4];
#pragma unroll
                    for (int r = 0; r < 4; ++r) pv[r] = __expf(sc[grp][s][r] - m_s[grp]);
                    ls += (pv[0] + pv[1]) + (pv[2] + pv[3]);
                    union { __bf16 hh[4]; u64 u; } pk;
                    pk.hh[0] = (__bf16)pv[0]; pk.hh[1] = (__bf16)pv[1];
                    pk.hh[2] = (__bf16)pv[2]; pk.hh[3] = (__bf16)pv[3];
                    *(u64*)&Ps[w][grp][lr][s * 16 + lg * 4] = pk.u;
                }
                ls += __shfl_xor(ls, 16);
                ls += __shfl_xor(ls, 32);
                l_s[grp] += ls;
            }

            // ---- P read + PV ----
            bf16x8 pf[2][2];
#pragma unroll
            for (int grp = 0; grp < 2; ++grp)
#pragma unroll
                for (int ks = 0; ks < 2; ++ks)
                    pf[grp][ks] = *(const bf16x8*)&Ps[w][grp][lr][ks * 32 + lg * 8];
#pragma unroll
            for (int n = 0; n < 8; ++n) {
                bf16x8 v0 = *(const bf16x8*)&Vs[cur][n * 16 + lr][lg * 8];
                bf16x8 v1 = *(const bf16x8*)&Vs[cur][n * 16 + lr][32 + lg * 8];
                __builtin_amdgcn_s_setprio(1);
                if (act0) {
                    O[0][n] = __builtin_amdgcn_mfma_f32_16x16x32_bf16(pf[0][0], v0, O[0][n], 0, 0, 0);
                    O[0][n] = __builtin_amdgcn_mfma_f32_16x16x32_bf16(pf[0][1], v1, O[0][n], 0, 0, 0);
                }
                if (act1) {
                    O[1][n] = __builtin_amdgcn_mfma_f32_16x16x32_bf16(pf[1][0], v0, O[1][n], 0, 0, 0);
                    O[1][n] = __builtin_amdgcn_mfma_f32_16x16x32_bf16(pf[1][1], v1, O[1][n], 0, 0, 0);
                }
                __builtin_amdgcn_s_setprio(0);
            }
        }

        if (hasNext) stage_write(cur ^ 1);
        __syncthreads();
        cur ^= 1;
    }

    // ---- epilogue ----
#pragma unroll
    for (int grp = 0; grp < 2; ++grp) {
        const float invl = 1.0f / l_s[grp];
        float inv[4];
#pragma unroll
        for (int r = 0; r < 4; ++r) inv[r] = __shfl(invl, lg * 4 + r);
#pragma unroll
        for (int n = 0; n < 8; ++n) {
#pragma unroll
            for (int r = 0; r < 4; ++r) {
                const size_t tt = (size_t)(b * SS + rg[grp] + lg * 4 + r);
                att[(tt * NHH + h) * 128 + n * 16 + lr] = (__bf16)(O[grp][n][r] * inv[r]);
            }
        }
    }
}

// ---------------------------------------------------------------------------
extern "C" void kernel_launch(void* const* d_in, const int* in_sizes, int n_in,
                              void* d_out, int out_size, void* d_ws, size_t ws_size,
                              hipStream_t stream) {
    (void)in_sizes; (void)n_in; (void)out_size; (void)ws_size;
    const float* x        = (const float*)d_in[0];
    const float* wq_down  = (const float*)d_in[1];
    const float* wq_up    = (const float*)d_in[2];
    const float* wq_rope  = (const float*)d_in[3];
    const float* q_norm_w = (const float*)d_in[4];
    const float* wkv_down = (const float*)d_in[5];
    const float* kv_norm_w= (const float*)d_in[6];
    const float* wkv_up   = (const float*)d_in[7];
    const float* wk_rope  = (const float*)d_in[8];
    const float* wo       = (const float*)d_in[9];
    float* out = (float*)d_out;

    char* ws = (char*)d_ws;
    float*  q_c   = (float*)(ws + 0);            // 24MB fp32 [4096][1536]
    __bf16* att   = (__bf16*)(ws + 0);           // 16MB bf16, aliases dead q_c
    float*  kv_c  = (float*)(ws + 25165824);     // 8MB fp32 [4096][512]
    __bf16* xb    = (__bf16*)(ws + 33554432);    // 16MB bf16 [4096][2048]
    __bf16* vT    = (__bf16*)(ws + 33554432);    // 16MB bf16, aliases dead xb
    __bf16* qc_b  = (__bf16*)(ws + 50331648);    // 12MB bf16 [4096][1536]
    __bf16* kvc_b = (__bf16*)(ws + 62914560);    // 4MB bf16 [4096][512]
    __bf16* krope = (__bf16*)(ws + 67108864);    // 0.5MB bf16 [4096][64]
    __bf16* qbuf  = (__bf16*)(ws + 67633152);    // 24MB bf16 [4096][3072]
    __bf16* wqd_b = (__bf16*)(ws + 92798976);    // 6MB
    __bf16* wqu_b = (__bf16*)(ws + 99090432);    // 6MB
    __bf16* wqr_b = (__bf16*)(ws + 105381888);   // 3MB
    __bf16* wkvd_b= (__bf16*)(ws + 108527616);   // 2MB
    __bf16* wkvu_b= (__bf16*)(ws + 110624768);   // 4MB
    __bf16* wkr_b = (__bf16*)(ws + 114819072);   // 0.25MB
    __bf16* wo_b  = (__bf16*)(ws + 115081216);   // 8MB (end 123469824)
    __bf16* knope = (__bf16*)d_out;              // 16MB bf16 in d_out (dead until final GEMM)

    const dim3 blk(256);

    cast_all<<<dim3(SEG7 / 2048), blk, 0, stream>>>(
        x, wq_down, wkv_down, wk_rope, wq_up, wq_rope, wkv_up, wo,
        xb, wqd_b, wkvd_b, wkr_b, wqu_b, wqr_b, wkvu_b, wo_b);

    // X-GEMM: 256 full tiles + 32 cheap strip tiles
    gemm10<0><<<dim3(288), dim3(512), 0, stream>>>(xb, wqd_b, wkvd_b, wkr_b,
                                                   q_c, kv_c, krope, nullptr, TT, 2112, 2048);

    rmsnorm2<<<dim3(2 * TT), blk, 0, stream>>>(q_c, kv_c, qc_b, kvc_b, q_norm_w, kv_norm_w);

    // fused Q-GEMM (384 tiles) + KV-GEMM (512 tiles) in one 896-block launch
    gemm10<1><<<dim3(896), dim3(512), 0, stream>>>(qc_b, wqu_b, wqr_b, wkvu_b,
                                                   (float*)kvc_b, (float*)vT,
                                                   qbuf, knope, TT, 3072, 1536);

    attn_mfma9<<<dim3(256), dim3(512), 0, stream>>>(qbuf, knope, krope, vT, att);

    gemm10<3><<<dim3(8, 32), dim3(512), 0, stream>>>(att, wo_b, nullptr, nullptr,
                                                     out, nullptr, nullptr, nullptr, TT, 2048, 2048);
}